// Round 4
// baseline (1398.539 us; speedup 1.0000x reference)
//
#include <hip/hip_runtime.h>

// PatternLearner on MI355X (gfx950). Inputs fp32, outputs fp32 (confirmed R3).
// d_out = 12.58M floats: [output0 (N*H) | output1=pattern (N*H)].
// Scratch-in-d_out: patb(bf16) bytes [0,12.58M), w1t..w2td bytes [12.58M,22.02M)
// — both inside output0's byte range, overwritten by the LAST kernel only.
// ws ~39 MB: vbuf | h1b (memb aliases h1b) | fp32 scalars.

#define N_TOK 8192
#define HDIM  768
#define H2DIM 1536
#define PMEM  8192
#define KTOP  16

typedef __attribute__((ext_vector_type(8))) short bf16x8;   // 8 bf16 = 4 VGPRs
typedef __attribute__((ext_vector_type(4))) float f32x4;
typedef unsigned short u16;
typedef unsigned int   u32;

__device__ __forceinline__ float bf2f(u16 u){ return __uint_as_float(((u32)u)<<16); }
__device__ __forceinline__ u16 f2bf(float f){
  u32 x = __float_as_uint(f);
  return (u16)((x + 0x7FFFu + ((x>>16)&1u)) >> 16);   // RNE
}

__device__ __forceinline__ float block_sum(float s){
  #pragma unroll
  for (int o=32;o;o>>=1) s += __shfl_xor(s,o);
  __shared__ float ps[4];
  int tid = threadIdx.x;
  if ((tid&63)==0) ps[tid>>6] = s;
  __syncthreads();
  return ps[0]+ps[1]+ps[2]+ps[3];
}

// ---- log0: v = atanh(nc)*x/nc, nc = clip(||x||,1e-5,1-1e-5). fp32 in, bf16 out
__global__ __launch_bounds__(256) void log0_rows(const float* __restrict__ in, u16* __restrict__ out){
  int r = blockIdx.x, tid = threadIdx.x;
  size_t ro = (size_t)r*HDIM;
  float v0=in[ro+tid], v1=in[ro+tid+256], v2=in[ro+tid+512];
  float s = block_sum(v0*v0+v1*v1+v2*v2);
  float n = sqrtf(s);
  float nc = fminf(fmaxf(n, 1e-5f), 1.0f-1e-5f);
  float sc = atanhf(nc)/nc;
  u16* orow = out + ro;
  orow[tid]=f2bf(v0*sc); orow[tid+256]=f2bf(v1*sc); orow[tid+512]=f2bf(v2*sc);
}

// ---- exp0: y = tanh(nm)*x/nm. bf16 in; fp32 out (+optional bf16 copy, a2/iva)
__global__ __launch_bounds__(256) void exp0_rows(const u16* __restrict__ in, float* __restrict__ outf,
                                                 u16* outb, float* a2p, float* ivp){
  int r = blockIdx.x, tid = threadIdx.x;
  const u16* row = in + (size_t)r*HDIM;
  float v0=bf2f(row[tid]), v1=bf2f(row[tid+256]), v2=bf2f(row[tid+512]);
  float s = block_sum(v0*v0+v1*v1+v2*v2);
  float n = sqrtf(s);
  float nm = fmaxf(n, 1e-5f);
  float sc = tanhf(nm)/nm;
  size_t ro = (size_t)r*HDIM;
  outf[ro+tid]=v0*sc; outf[ro+tid+256]=v1*sc; outf[ro+tid+512]=v2*sc;
  if (outb != nullptr){
    outb[ro+tid]=f2bf(v0*sc); outb[ro+tid+256]=f2bf(v1*sc); outb[ro+tid+512]=f2bf(v2*sc);
  }
  if (a2p != nullptr && tid==0){
    float a2 = fminf(sc*sc*s, 1.0f-1e-5f);
    a2p[r] = a2; ivp[r] = 1.0f/(1.0f-a2);
  }
}

// ---- memory prep: memb(bf16), b2, 1/(1-b2), sigmoid(importance). fp32 in
__global__ __launch_bounds__(256) void prep_mem(const float* __restrict__ mem, const float* __restrict__ imp,
                                                u16* __restrict__ memb,
                                                float* b2p, float* ivb, float* sgp){
  int p = blockIdx.x, tid = threadIdx.x;
  size_t ro = (size_t)p*HDIM;
  float v0=mem[ro+tid], v1=mem[ro+tid+256], v2=mem[ro+tid+512];
  memb[ro+tid]=f2bf(v0); memb[ro+tid+256]=f2bf(v1); memb[ro+tid+512]=f2bf(v2);
  float s = block_sum(v0*v0+v1*v1+v2*v2);
  if (tid==0){
    float b2 = fminf(s, 1.0f-1e-5f);
    b2p[p]=b2; ivb[p]=1.0f/(1.0f-b2);
    sgp[p] = 1.0f/(1.0f+expf(-imp[p]));
  }
}

// ---- LayerNorm + exact gelu over rows of 1536; in-place safe. g/be fp32 ----
__global__ __launch_bounds__(256) void ln_gelu(const u16* __restrict__ in, const float* __restrict__ g,
                                               const float* __restrict__ be, u16* __restrict__ out){
  int r = blockIdx.x, tid = threadIdx.x;
  const u16* row = in + (size_t)r*H2DIM;
  float h[6]; float s=0.f, s2=0.f;
  #pragma unroll
  for (int j=0;j<6;j++){ float v=bf2f(row[tid+256*j]); h[j]=v; s+=v; s2+=v*v; }
  #pragma unroll
  for (int o=32;o;o>>=1){ s += __shfl_xor(s,o); s2 += __shfl_xor(s2,o); }
  __shared__ float ps[4], ps2[4];
  if ((tid&63)==0){ ps[tid>>6]=s; ps2[tid>>6]=s2; }
  __syncthreads();
  s = ps[0]+ps[1]+ps[2]+ps[3]; s2 = ps2[0]+ps2[1]+ps2[2]+ps2[3];
  float mu  = s*(1.0f/H2DIM);
  float var = fmaxf(s2*(1.0f/H2DIM) - mu*mu, 0.0f);
  float rstd = rsqrtf(var + 1e-5f);
  u16* orow = out + (size_t)r*H2DIM;
  #pragma unroll
  for (int j=0;j<6;j++){
    int c = tid+256*j;
    float y = (h[j]-mu)*rstd*g[c] + be[c];
    float ge = 0.5f*y*(1.0f + erff(y*0.70710678118654752f));
    orow[c] = f2bf(ge);
  }
}

// ---- GEMM: C[M,N] = A[M,K]*BT[N,K]^T + bias; bf16 in/out, fp32 acc/bias ----
__global__ __launch_bounds__(256,2) void gemm_bt(
    const u16* __restrict__ A, const u16* __restrict__ B,
    const float* __restrict__ bias, u16* __restrict__ C,
    int M, int Nn, int Kk)
{
  __shared__ u16 As[128][40];
  __shared__ u16 Bs[128][40];
  const int tid = threadIdx.x;
  const int m0 = blockIdx.y*128, n0 = blockIdx.x*128;
  const int wave = tid>>6, lane = tid&63;
  const int wm = (wave>>1)*64, wn = (wave&1)*64;
  const int col = lane&15, quad = lane>>4;
  const int sr = tid>>1, scol = (tid&1)*16;
  f32x4 acc[4][4] = {};
  for (int k0=0; k0<Kk; k0+=32){
    bf16x8 av0 = *(const bf16x8*)(A + (size_t)(m0+sr)*Kk + k0 + scol);
    bf16x8 av1 = *(const bf16x8*)(A + (size_t)(m0+sr)*Kk + k0 + scol + 8);
    bf16x8 bv0 = *(const bf16x8*)(B + (size_t)(n0+sr)*Kk + k0 + scol);
    bf16x8 bv1 = *(const bf16x8*)(B + (size_t)(n0+sr)*Kk + k0 + scol + 8);
    __syncthreads();
    *(bf16x8*)&As[sr][scol] = av0;  *(bf16x8*)&As[sr][scol+8] = av1;
    *(bf16x8*)&Bs[sr][scol] = bv0;  *(bf16x8*)&Bs[sr][scol+8] = bv1;
    __syncthreads();
    bf16x8 af[4], bfr[4];
    #pragma unroll
    for (int i=0;i<4;i++) af[i]  = *(const bf16x8*)&As[wm+i*16+col][quad*8];
    #pragma unroll
    for (int j=0;j<4;j++) bfr[j] = *(const bf16x8*)&Bs[wn+j*16+col][quad*8];
    #pragma unroll
    for (int i=0;i<4;i++)
      #pragma unroll
      for (int j=0;j<4;j++)
        acc[i][j] = __builtin_amdgcn_mfma_f32_16x16x32_bf16(af[i], bfr[j], acc[i][j], 0,0,0);
  }
  #pragma unroll
  for (int j=0;j<4;j++){
    int cc = n0 + wn + j*16 + col;
    float bv = bias[cc];
    #pragma unroll
    for (int i=0;i<4;i++){
      int rbase = m0 + wm + i*16 + quad*4;
      #pragma unroll
      for (int rr=0;rr<4;rr++)
        C[(size_t)(rbase+rr)*Nn + cc] = f2bf(acc[i][j][rr] + bv);
    }
  }
}

// ---- transpose fp32 -> bf16: in[R][C] -> out[C][R] (R,C %32==0) ----
__global__ __launch_bounds__(256) void transpose_f2b(const float* __restrict__ in, u16* __restrict__ out,
                                                     int R, int Ccols){
  __shared__ float tile[32][33];
  int tx = threadIdx.x & 31, ty = threadIdx.x >> 5;
  int c0 = blockIdx.x*32, r0 = blockIdx.y*32;
  #pragma unroll
  for (int i=0;i<32;i+=8) tile[ty+i][tx] = in[(size_t)(r0+ty+i)*Ccols + c0+tx];
  __syncthreads();
  #pragma unroll
  for (int i=0;i<32;i+=8) out[(size_t)(c0+ty+i)*R + r0+tx] = f2bf(tile[tx][ty+i]);
}

// ---- fused poincare-dist + top-16. 16 tokens/block, sweep all P patterns ----
// packed candidate = (dist_f32_bits & ~0x1FFF) | pattern_idx  (P=8192=2^13)
__global__ __launch_bounds__(256,2) void dist_topk(
    const u16* __restrict__ patb, const u16* __restrict__ memb,
    const float* __restrict__ a2f, const float* __restrict__ iva,
    const float* __restrict__ b2p, const float* __restrict__ ivb,
    const float* __restrict__ sgp,
    float* __restrict__ wkb, int* __restrict__ ikb)
{
  __shared__ u16 As[16][776];        // 768 + 8 pad
  __shared__ u32 cand[4][16][64];
  __shared__ u32 lists[4][16][16];   // per-wave sorted-16 (ascending)
  __shared__ float a2s[16], ivs[16];
  const int tid = threadIdx.x;
  const int t0 = blockIdx.x*16;
  #pragma unroll
  for (int j=0;j<6;j++){
    int li = tid + 256*j;
    int row = li/96, c8 = li%96;
    *(bf16x8*)&As[row][c8*8] = *(const bf16x8*)(patb + (size_t)(t0+row)*HDIM + c8*8);
  }
  if (tid<16){ a2s[tid]=a2f[t0+tid]; ivs[tid]=iva[t0+tid]; }
  #pragma unroll
  for (int j=0;j<4;j++) ((u32*)lists)[tid*4+j] = 0xFFFFFFFFu;
  __syncthreads();
  const int wave = tid>>6, lane = tid&63;
  const int col = lane&15, quad = lane>>4;
  for (int c=0;c<32;c++){
    int pbase = c*256 + wave*64;
    f32x4 acc[4] = {};
    #pragma unroll 4
    for (int kk=0;kk<24;kk++){
      bf16x8 a = *(const bf16x8*)&As[col][kk*32 + quad*8];   // A[m=lane&15][k=quad*8+j]
      #pragma unroll
      for (int cg=0;cg<4;cg++){
        const u16* bp = memb + (size_t)(pbase+cg*16+col)*HDIM + kk*32 + quad*8;
        bf16x8 b = *(const bf16x8*)bp;                       // B[n=lane&15][k=quad*8+j]
        acc[cg] = __builtin_amdgcn_mfma_f32_16x16x32_bf16(a, b, acc[cg], 0,0,0);
      }
    }
    #pragma unroll
    for (int cg=0;cg<4;cg++){
      int p = pbase + cg*16 + col;
      float b2v = b2p[p], ibv = ivb[p], sgv = sgp[p];
      #pragma unroll
      for (int rr=0;rr<4;rr++){
        int tt = quad*4 + rr;        // C row = token within tile
        float num = fmaxf(a2s[tt] + b2v - 2.0f*acc[cg][rr], 0.0f);
        float arg = fmaf(2.0f*num, ivs[tt]*ibv, 1.0f);
        float d = acoshf(fmaxf(arg, 1.0000001f)) * sgv;
        cand[wave][tt][cg*16+col] = (__float_as_uint(d) & 0xFFFFE000u) | (u32)p;
      }
    }
    __syncthreads();
    if (lane < 16){                  // lane t maintains token t's per-wave top-16
      u32* lst = &lists[wave][lane][0];
      u32 worst = lst[15];
      for (int i=0;i<64;i++){
        u32 v = cand[wave][lane][i];
        if (v < worst){
          int j = 15;
          while (j>0 && lst[j-1] > v){ lst[j] = lst[j-1]; --j; }
          lst[j] = v;
          worst = lst[15];
        }
      }
    }
    __syncthreads();
  }
  if (tid < 16){                     // 4-way merge of sorted lists -> global top-16
    int ptr[4] = {0,0,0,0};
    for (int j=0;j<KTOP;j++){
      u32 best = 0xFFFFFFFFu; int bw = 0;
      #pragma unroll
      for (int w2=0;w2<4;w2++){
        u32 v = (ptr[w2]<16) ? lists[w2][tid][ptr[w2]] : 0xFFFFFFFFu;
        if (v < best){ best = v; bw = w2; }
      }
      ptr[bw]++;
      float d = __uint_as_float(best & 0xFFFFE000u);
      wkb[(size_t)(t0+tid)*KTOP + j] = expf(-d);
      ikb[(size_t)(t0+tid)*KTOP + j] = (int)(best & 0x1FFFu);
    }
  }
}

// ---- fused: processed = sum_k w_k*memb[idx_k]; out = log0(processed) bf16 ----
__global__ __launch_bounds__(256) void gather_log0(
    const float* __restrict__ wkb, const int* __restrict__ ikb,
    const u16* __restrict__ memb, u16* __restrict__ out)
{
  __shared__ float wsh[KTOP]; __shared__ int ish[KTOP];
  int n = blockIdx.x, tid = threadIdx.x;
  if (tid < KTOP){ wsh[tid] = wkb[(size_t)n*KTOP+tid]; ish[tid] = ikb[(size_t)n*KTOP+tid]; }
  __syncthreads();
  float v[3];
  #pragma unroll
  for (int j=0;j<3;j++){
    int cdx = tid + 256*j;
    float s = 0.f;
    #pragma unroll
    for (int k=0;k<KTOP;k++) s += wsh[k]*bf2f(memb[(size_t)ish[k]*HDIM + cdx]);
    v[j] = s;
  }
  float ss = block_sum(v[0]*v[0]+v[1]*v[1]+v[2]*v[2]);
  float nn = sqrtf(ss);
  float nc = fminf(fmaxf(nn, 1e-5f), 1.0f-1e-5f);
  float sc = atanhf(nc)/nc;
  #pragma unroll
  for (int j=0;j<3;j++) out[(size_t)n*HDIM + tid + 256*j] = f2bf(v[j]*sc);
}

extern "C" void kernel_launch(void* const* d_in, const int* in_sizes, int n_in,
                              void* d_out, int out_size, void* d_ws, size_t ws_size,
                              hipStream_t stream)
{
  const float* x    = (const float*)d_in[0];
  const float* ew1  = (const float*)d_in[1];
  const float* eb1  = (const float*)d_in[2];
  const float* eg   = (const float*)d_in[3];
  const float* ebe  = (const float*)d_in[4];
  const float* ew2  = (const float*)d_in[5];
  const float* eb2  = (const float*)d_in[6];
  const float* dw1  = (const float*)d_in[7];
  const float* db1  = (const float*)d_in[8];
  const float* dg   = (const float*)d_in[9];
  const float* dbe  = (const float*)d_in[10];
  const float* dw2  = (const float*)d_in[11];
  const float* db2  = (const float*)d_in[12];
  const float* mem  = (const float*)d_in[13];
  const float* imp  = (const float*)d_in[14];

  const size_t NE = (size_t)N_TOK*HDIM;       // 6,291,456
  float* out0 = (float*)d_out;                // fp32 output 0, bytes [0, 25.17M)
  float* out1 = out0 + NE;                    // fp32 output 1 (pattern), bytes [25.17M, 50.33M)
  // scratch inside output0's byte range (overwritten by the final exp0 only):
  u16* patb = (u16*)d_out;                    // bf16 pattern, bytes [0, 12.58M)
  const size_t SWE = (size_t)HDIM*H2DIM;      // 1,179,648
  u16* w1t  = (u16*)d_out + NE;               // bytes [12.58M, ...)
  u16* w2t  = w1t + SWE;
  u16* w1td = w1t + 2*SWE;
  u16* w2td = w1t + 3*SWE;                    // ends at byte 22.02M < 25.17M

  char* w = (char*)d_ws;
  size_t off = 0;
  u16* vbuf = (u16*)(w+off); off += NE*2;                    // bf16, also h2 alias
  u16* h1b  = (u16*)(w+off); off += (size_t)N_TOK*H2DIM*2;   // bf16; ln_gelu in-place
  u16* memb = h1b;                                            // alias: live enc-end..gather only
  float* a2f = (float*)(w+off); off += (size_t)N_TOK*4;
  float* iva = (float*)(w+off); off += (size_t)N_TOK*4;
  float* b2p = (float*)(w+off); off += (size_t)PMEM*4;
  float* ivb = (float*)(w+off); off += (size_t)PMEM*4;
  float* sgp = (float*)(w+off); off += (size_t)PMEM*4;
  float* wkb = (float*)(w+off); off += (size_t)N_TOK*KTOP*4;
  int*   ikb = (int*)(w+off);   off += (size_t)N_TOK*KTOP*4;
  (void)in_sizes; (void)n_in; (void)out_size; (void)ws_size;

  dim3 blk(256);
  transpose_f2b<<<dim3(H2DIM/32, HDIM/32), blk, 0, stream>>>(ew1, w1t,  HDIM,  H2DIM);
  transpose_f2b<<<dim3(HDIM/32, H2DIM/32), blk, 0, stream>>>(ew2, w2t,  H2DIM, HDIM);
  transpose_f2b<<<dim3(H2DIM/32, HDIM/32), blk, 0, stream>>>(dw1, w1td, HDIM,  H2DIM);
  transpose_f2b<<<dim3(HDIM/32, H2DIM/32), blk, 0, stream>>>(dw2, w2td, H2DIM, HDIM);
  // encoder
  log0_rows<<<N_TOK, blk, 0, stream>>>(x, vbuf);
  gemm_bt<<<dim3(H2DIM/128, N_TOK/128), blk, 0, stream>>>(vbuf, w1t, eb1, h1b, N_TOK, H2DIM, HDIM);
  ln_gelu<<<N_TOK, blk, 0, stream>>>(h1b, eg, ebe, h1b);
  gemm_bt<<<dim3(HDIM/128, N_TOK/128), blk, 0, stream>>>(h1b, w2t, eb2, vbuf, N_TOK, HDIM, H2DIM);
  exp0_rows<<<N_TOK, blk, 0, stream>>>(vbuf, out1, patb, a2f, iva);   // fp32 pattern + bf16 copy
  // retrieval (memb aliases h1b — dead between encoder and decoder)
  prep_mem<<<PMEM, blk, 0, stream>>>(mem, imp, memb, b2p, ivb, sgp);
  dist_topk<<<N_TOK/16, blk, 0, stream>>>(patb, memb, a2f, iva, b2p, ivb, sgp, wkb, ikb);
  gather_log0<<<N_TOK, blk, 0, stream>>>(wkb, ikb, memb, vbuf);
  // decoder
  gemm_bt<<<dim3(H2DIM/128, N_TOK/128), blk, 0, stream>>>(vbuf, w1td, db1, h1b, N_TOK, H2DIM, HDIM);
  ln_gelu<<<N_TOK, blk, 0, stream>>>(h1b, dg, dbe, h1b);
  gemm_bt<<<dim3(HDIM/128, N_TOK/128), blk, 0, stream>>>(h1b, w2td, db2, vbuf, N_TOK, HDIM, H2DIM);
  exp0_rows<<<N_TOK, blk, 0, stream>>>(vbuf, out0, nullptr, nullptr, nullptr);  // fp32 output 0 (last)
}

// Round 5
// 1256.412 us; speedup vs baseline: 1.1131x; 1.1131x over previous
//
#include <hip/hip_runtime.h>

// PatternLearner on MI355X (gfx950). Inputs fp32, outputs fp32.
// d_out = [output0 (N*H) | output1=pattern (N*H)] fp32.
// Scratch-in-d_out: patb(bf16) bytes [0,12.58M), w1t..w2td bytes [12.58M,22.02M)
// — inside output0's byte range, overwritten only by the final exp0.
// ws ~40 MB: vbuf | h1b (memb aliases h1b) | pmeta | a2f/iva | plist.

#define N_TOK 8192
#define HDIM  768
#define H2DIM 1536
#define PMEM  8192
#define KTOP  16

typedef __attribute__((ext_vector_type(8))) short bf16x8;   // 8 bf16 = 4 VGPRs
typedef __attribute__((ext_vector_type(4))) float f32x4;
typedef unsigned short u16;
typedef unsigned int   u32;

__device__ __forceinline__ float bf2f(u16 u){ return __uint_as_float(((u32)u)<<16); }
__device__ __forceinline__ u16 f2bf(float f){
  u32 x = __float_as_uint(f);
  return (u16)((x + 0x7FFFu + ((x>>16)&1u)) >> 16);   // RNE
}

__device__ __forceinline__ float block_sum(float s){
  #pragma unroll
  for (int o=32;o;o>>=1) s += __shfl_xor(s,o);
  __shared__ float ps[4];
  int tid = threadIdx.x;
  if ((tid&63)==0) ps[tid>>6] = s;
  __syncthreads();
  return ps[0]+ps[1]+ps[2]+ps[3];
}

// ---- log0: v = atanh(nc)*x/nc. fp32 in, bf16 out ----
__global__ __launch_bounds__(256) void log0_rows(const float* __restrict__ in, u16* __restrict__ out){
  int r = blockIdx.x, tid = threadIdx.x;
  size_t ro = (size_t)r*HDIM;
  float v0=in[ro+tid], v1=in[ro+tid+256], v2=in[ro+tid+512];
  float s = block_sum(v0*v0+v1*v1+v2*v2);
  float n = sqrtf(s);
  float nc = fminf(fmaxf(n, 1e-5f), 1.0f-1e-5f);
  float sc = atanhf(nc)/nc;
  u16* orow = out + ro;
  orow[tid]=f2bf(v0*sc); orow[tid+256]=f2bf(v1*sc); orow[tid+512]=f2bf(v2*sc);
}

// ---- exp0: y = tanh(nm)*x/nm. bf16 in; fp32 out (+optional bf16 copy, a2/iva)
__global__ __launch_bounds__(256) void exp0_rows(const u16* __restrict__ in, float* __restrict__ outf,
                                                 u16* outb, float* a2p, float* ivp){
  int r = blockIdx.x, tid = threadIdx.x;
  const u16* row = in + (size_t)r*HDIM;
  float v0=bf2f(row[tid]), v1=bf2f(row[tid+256]), v2=bf2f(row[tid+512]);
  float s = block_sum(v0*v0+v1*v1+v2*v2);
  float n = sqrtf(s);
  float nm = fmaxf(n, 1e-5f);
  float sc = tanhf(nm)/nm;
  size_t ro = (size_t)r*HDIM;
  outf[ro+tid]=v0*sc; outf[ro+tid+256]=v1*sc; outf[ro+tid+512]=v2*sc;
  if (outb != nullptr){
    outb[ro+tid]=f2bf(v0*sc); outb[ro+tid+256]=f2bf(v1*sc); outb[ro+tid+512]=f2bf(v2*sc);
  }
  if (a2p != nullptr && tid==0){
    float a2 = fminf(sc*sc*s, 1.0f-1e-5f);
    a2p[r] = a2; ivp[r] = 1.0f/(1.0f-a2);
  }
}

// ---- memory prep: memb(bf16), pmeta = {b2, 1/(1-b2), sigmoid(imp), 0} ----
__global__ __launch_bounds__(256) void prep_mem(const float* __restrict__ mem, const float* __restrict__ imp,
                                                u16* __restrict__ memb, float4* __restrict__ pmeta){
  int p = blockIdx.x, tid = threadIdx.x;
  size_t ro = (size_t)p*HDIM;
  float v0=mem[ro+tid], v1=mem[ro+tid+256], v2=mem[ro+tid+512];
  memb[ro+tid]=f2bf(v0); memb[ro+tid+256]=f2bf(v1); memb[ro+tid+512]=f2bf(v2);
  float s = block_sum(v0*v0+v1*v1+v2*v2);
  if (tid==0){
    float b2 = fminf(s, 1.0f-1e-5f);
    float4 m; m.x=b2; m.y=1.0f/(1.0f-b2); m.z=1.0f/(1.0f+__expf(-imp[p])); m.w=0.f;
    pmeta[p]=m;
  }
}

// ---- LayerNorm + exact gelu over rows of 1536; in-place safe ----
__global__ __launch_bounds__(256) void ln_gelu(const u16* __restrict__ in, const float* __restrict__ g,
                                               const float* __restrict__ be, u16* __restrict__ out){
  int r = blockIdx.x, tid = threadIdx.x;
  const u16* row = in + (size_t)r*H2DIM;
  float h[6]; float s=0.f, s2=0.f;
  #pragma unroll
  for (int j=0;j<6;j++){ float v=bf2f(row[tid+256*j]); h[j]=v; s+=v; s2+=v*v; }
  #pragma unroll
  for (int o=32;o;o>>=1){ s += __shfl_xor(s,o); s2 += __shfl_xor(s2,o); }
  __shared__ float ps[4], ps2[4];
  if ((tid&63)==0){ ps[tid>>6]=s; ps2[tid>>6]=s2; }
  __syncthreads();
  s = ps[0]+ps[1]+ps[2]+ps[3]; s2 = ps2[0]+ps2[1]+ps2[2]+ps2[3];
  float mu  = s*(1.0f/H2DIM);
  float var = fmaxf(s2*(1.0f/H2DIM) - mu*mu, 0.0f);
  float rstd = rsqrtf(var + 1e-5f);
  u16* orow = out + (size_t)r*H2DIM;
  #pragma unroll
  for (int j=0;j<6;j++){
    int c = tid+256*j;
    float y = (h[j]-mu)*rstd*g[c] + be[c];
    float ge = 0.5f*y*(1.0f + erff(y*0.70710678118654752f));
    orow[c] = f2bf(ge);
  }
}

// ---- GEMM: C[M,N] = A[M,K]*BT[N,K]^T + bias; bf16 in/out, fp32 acc/bias ----
__global__ __launch_bounds__(256,2) void gemm_bt(
    const u16* __restrict__ A, const u16* __restrict__ B,
    const float* __restrict__ bias, u16* __restrict__ C,
    int M, int Nn, int Kk)
{
  __shared__ u16 As[128][40];
  __shared__ u16 Bs[128][40];
  const int tid = threadIdx.x;
  const int m0 = blockIdx.y*128, n0 = blockIdx.x*128;
  const int wave = tid>>6, lane = tid&63;
  const int wm = (wave>>1)*64, wn = (wave&1)*64;
  const int col = lane&15, quad = lane>>4;
  const int sr = tid>>1, scol = (tid&1)*16;
  f32x4 acc[4][4] = {};
  for (int k0=0; k0<Kk; k0+=32){
    bf16x8 av0 = *(const bf16x8*)(A + (size_t)(m0+sr)*Kk + k0 + scol);
    bf16x8 av1 = *(const bf16x8*)(A + (size_t)(m0+sr)*Kk + k0 + scol + 8);
    bf16x8 bv0 = *(const bf16x8*)(B + (size_t)(n0+sr)*Kk + k0 + scol);
    bf16x8 bv1 = *(const bf16x8*)(B + (size_t)(n0+sr)*Kk + k0 + scol + 8);
    __syncthreads();
    *(bf16x8*)&As[sr][scol] = av0;  *(bf16x8*)&As[sr][scol+8] = av1;
    *(bf16x8*)&Bs[sr][scol] = bv0;  *(bf16x8*)&Bs[sr][scol+8] = bv1;
    __syncthreads();
    bf16x8 af[4], bfr[4];
    #pragma unroll
    for (int i=0;i<4;i++) af[i]  = *(const bf16x8*)&As[wm+i*16+col][quad*8];
    #pragma unroll
    for (int j=0;j<4;j++) bfr[j] = *(const bf16x8*)&Bs[wn+j*16+col][quad*8];
    #pragma unroll
    for (int i=0;i<4;i++)
      #pragma unroll
      for (int j=0;j<4;j++)
        acc[i][j] = __builtin_amdgcn_mfma_f32_16x16x32_bf16(af[i], bfr[j], acc[i][j], 0,0,0);
  }
  #pragma unroll
  for (int j=0;j<4;j++){
    int cc = n0 + wn + j*16 + col;
    float bv = bias[cc];
    #pragma unroll
    for (int i=0;i<4;i++){
      int rbase = m0 + wm + i*16 + quad*4;
      #pragma unroll
      for (int rr=0;rr<4;rr++)
        C[(size_t)(rbase+rr)*Nn + cc] = f2bf(acc[i][j][rr] + bv);
    }
  }
}

// ---- transpose fp32 -> bf16 ----
__global__ __launch_bounds__(256) void transpose_f2b(const float* __restrict__ in, u16* __restrict__ out,
                                                     int R, int Ccols){
  __shared__ float tile[32][33];
  int tx = threadIdx.x & 31, ty = threadIdx.x >> 5;
  int c0 = blockIdx.x*32, r0 = blockIdx.y*32;
  #pragma unroll
  for (int i=0;i<32;i+=8) tile[ty+i][tx] = in[(size_t)(r0+ty+i)*Ccols + c0+tx];
  __syncthreads();
  #pragma unroll
  for (int i=0;i<32;i+=8) out[(size_t)(c0+ty+i)*R + r0+tx] = f2bf(tile[tx][ty+i]);
}

// ---- fused poincare-dist + top-16, survivor-filtered selection ----
// grid (N_TOK/16, 2): blockIdx.y = pattern half (4096 each). 16 tokens/block.
// packed key = (dist_f32_bits & ~0x1FFF) | global_pattern_idx (13 bits).
// Per-wave sorted-16 lists; in-block 4-way merge -> plist[token][half][16].
__global__ __launch_bounds__(256,3) void dist_topk(
    const u16* __restrict__ patb, const u16* __restrict__ memb,
    const float* __restrict__ a2f, const float* __restrict__ iva,
    const float4* __restrict__ pmeta, u32* __restrict__ plist)
{
  __shared__ u16 As[16][772];        // stride 772: bank stride 2 per row -> conflict-free
  __shared__ u32 cand[4][64][17];    // [wave][i=cg*16+col][token], 17-pad
  __shared__ u32 lists[4][16][17];   // per-wave sorted-16 ascending, 17-pad
  __shared__ u32 masks[4][64];       // per-producer-lane survivor bitmask
  __shared__ float a2s[16], ivs[16];
  const int tid = threadIdx.x;
  const int t0 = blockIdx.x*16;
  const int h  = blockIdx.y;         // pattern half
  #pragma unroll
  for (int j=0;j<6;j++){
    int li = tid + 256*j;            // 16 rows x 96 vec8 chunks
    int row = li/96, c8 = li%96;
    *(bf16x8*)&As[row][c8*8] = *(const bf16x8*)(patb + (size_t)(t0+row)*HDIM + c8*8);
  }
  if (tid<16){ a2s[tid]=a2f[t0+tid]; ivs[tid]=iva[t0+tid]; }
  {
    int w2 = tid>>6, r2 = tid&63;
    if (r2 < 16){
      #pragma unroll
      for (int j=0;j<17;j++) lists[w2][r2][j] = 0xFFFFFFFFu;
    }
  }
  __syncthreads();
  const int wave = tid>>6, lane = tid&63;
  const int col = lane&15, quad = lane>>4;
  for (int c=0;c<16;c++){
    int pbase = h*4096 + c*256 + wave*64;
    // ---- MFMA phase: 16 tokens x 64 patterns x K=768, depth-2 B prefetch ----
    const u16* brow0 = memb + (size_t)(pbase+ 0+col)*HDIM + quad*8;
    const u16* brow1 = memb + (size_t)(pbase+16+col)*HDIM + quad*8;
    const u16* brow2 = memb + (size_t)(pbase+32+col)*HDIM + quad*8;
    const u16* brow3 = memb + (size_t)(pbase+48+col)*HDIM + quad*8;
    bf16x8 bA[4], bB[4];
    bA[0]=*(const bf16x8*)(brow0); bA[1]=*(const bf16x8*)(brow1);
    bA[2]=*(const bf16x8*)(brow2); bA[3]=*(const bf16x8*)(brow3);
    bB[0]=*(const bf16x8*)(brow0+32); bB[1]=*(const bf16x8*)(brow1+32);
    bB[2]=*(const bf16x8*)(brow2+32); bB[3]=*(const bf16x8*)(brow3+32);
    f32x4 acc[4] = {};
    #pragma unroll
    for (int kk=0;kk<24;kk++){
      bf16x8 a = *(const bf16x8*)&As[col][kk*32 + quad*8];
      if ((kk&1)==0){
        #pragma unroll
        for (int cg=0;cg<4;cg++)
          acc[cg] = __builtin_amdgcn_mfma_f32_16x16x32_bf16(a, bA[cg], acc[cg], 0,0,0);
        if (kk+2 < 24){
          int ko = (kk+2)*32;
          bA[0]=*(const bf16x8*)(brow0+ko); bA[1]=*(const bf16x8*)(brow1+ko);
          bA[2]=*(const bf16x8*)(brow2+ko); bA[3]=*(const bf16x8*)(brow3+ko);
        }
      } else {
        #pragma unroll
        for (int cg=0;cg<4;cg++)
          acc[cg] = __builtin_amdgcn_mfma_f32_16x16x32_bf16(a, bB[cg], acc[cg], 0,0,0);
        if (kk+2 < 24){
          int ko = (kk+2)*32;
          bB[0]=*(const bf16x8*)(brow0+ko); bB[1]=*(const bf16x8*)(brow1+ko);
          bB[2]=*(const bf16x8*)(brow2+ko); bB[3]=*(const bf16x8*)(brow3+ko);
        }
      }
    }
    // ---- epilogue: dist + survivor filter (registers -> LDS only if < thr) ----
    u32 thrU[4];
    #pragma unroll
    for (int rr=0;rr<4;rr++) thrU[rr] = lists[wave][quad*4+rr][15];
    u32 mask = 0;
    #pragma unroll
    for (int cg=0;cg<4;cg++){
      int p = pbase + cg*16 + col;
      float4 mt = pmeta[p];
      #pragma unroll
      for (int rr=0;rr<4;rr++){
        int tt = quad*4 + rr;
        float num = fmaxf(a2s[tt] + mt.x - 2.0f*acc[cg][rr], 0.0f);
        float arg = fmaf(2.0f*num, ivs[tt]*mt.y, 1.0f);
        arg = fmaxf(arg, 1.0000001f);
        float d = __logf(arg + sqrtf((arg-1.0f)*(arg+1.0f))) * mt.z;  // acosh*sig
        u32 key = (__float_as_uint(d) & 0xFFFFE000u) | (u32)p;
        if (key < thrU[rr]){
          cand[wave][cg*16+col][tt] = key;
          mask |= 1u << (rr*4+cg);
        }
      }
    }
    masks[wave][lane] = mask;
    __syncthreads();
    // ---- serial phase: lane tt<16 of each wave drains survivors for token tt
    if (lane < 16){
      const int g = lane>>2, rr = lane&3;
      u32* lst = &lists[wave][lane][0];
      u32 worst = lst[15];
      #pragma unroll 4
      for (int q=0;q<16;q++){
        u32 m = (masks[wave][g*16+q] >> (rr*4)) & 0xFu;
        while (m){
          int cg = __ffs(m)-1; m &= m-1;
          u32 v = cand[wave][cg*16+q][lane];
          if (v < worst){
            int j = 15;
            while (j>0 && lst[j-1] > v){ lst[j] = lst[j-1]; --j; }
            lst[j] = v;
            worst = lst[15];
          }
        }
      }
    }
    __syncthreads();
  }
  // ---- in-block 4-way merge of per-wave lists -> plist[token][h][16] ----
  if (tid < 16){
    int ptr[4] = {0,0,0,0};
    u32* dst = plist + ((size_t)(t0+tid)*2 + h)*16;
    for (int j=0;j<KTOP;j++){
      u32 best = 0xFFFFFFFFu; int bw = 0;
      #pragma unroll
      for (int w2=0;w2<4;w2++){
        u32 v = (ptr[w2]<16) ? lists[w2][tid][ptr[w2]] : 0xFFFFFFFFu;
        if (v < best){ best = v; bw = w2; }
      }
      ptr[bw]++;
      dst[j] = best;
    }
  }
}

// ---- fused: merge 2 halves' top-16, gather, log0 ----
__global__ __launch_bounds__(256) void gather_log0(
    const u32* __restrict__ plist, const u16* __restrict__ memb, u16* __restrict__ out)
{
  __shared__ float wsh[KTOP]; __shared__ int ish[KTOP];
  int n = blockIdx.x, tid = threadIdx.x;
  if (tid == 0){
    const u32* l0 = plist + (size_t)n*32;
    const u32* l1 = l0 + 16;
    int p0=0, p1=0;
    #pragma unroll
    for (int j=0;j<KTOP;j++){
      u32 a = l0[p0], b = l1[p1];
      u32 best; if (a < b){ best=a; p0++; } else { best=b; p1++; }
      wsh[j] = __expf(-__uint_as_float(best & 0xFFFFE000u));
      ish[j] = (int)(best & 0x1FFFu);
    }
  }
  __syncthreads();
  float v[3];
  #pragma unroll
  for (int j=0;j<3;j++){
    int cdx = tid + 256*j;
    float s = 0.f;
    #pragma unroll
    for (int k=0;k<KTOP;k++) s += wsh[k]*bf2f(memb[(size_t)ish[k]*HDIM + cdx]);
    v[j] = s;
  }
  float ss = block_sum(v[0]*v[0]+v[1]*v[1]+v[2]*v[2]);
  float nn = sqrtf(ss);
  float nc = fminf(fmaxf(nn, 1e-5f), 1.0f-1e-5f);
  float sc = atanhf(nc)/nc;
  #pragma unroll
  for (int j=0;j<3;j++) out[(size_t)n*HDIM + tid + 256*j] = f2bf(v[j]*sc);
}

extern "C" void kernel_launch(void* const* d_in, const int* in_sizes, int n_in,
                              void* d_out, int out_size, void* d_ws, size_t ws_size,
                              hipStream_t stream)
{
  const float* x    = (const float*)d_in[0];
  const float* ew1  = (const float*)d_in[1];
  const float* eb1  = (const float*)d_in[2];
  const float* eg   = (const float*)d_in[3];
  const float* ebe  = (const float*)d_in[4];
  const float* ew2  = (const float*)d_in[5];
  const float* eb2  = (const float*)d_in[6];
  const float* dw1  = (const float*)d_in[7];
  const float* db1  = (const float*)d_in[8];
  const float* dg   = (const float*)d_in[9];
  const float* dbe  = (const float*)d_in[10];
  const float* dw2  = (const float*)d_in[11];
  const float* db2  = (const float*)d_in[12];
  const float* mem  = (const float*)d_in[13];
  const float* imp  = (const float*)d_in[14];

  const size_t NE = (size_t)N_TOK*HDIM;       // 6,291,456
  float* out0 = (float*)d_out;                // fp32 output 0
  float* out1 = out0 + NE;                    // fp32 output 1 (pattern)
  u16* patb = (u16*)d_out;                    // bf16 pattern, inside output0 range
  const size_t SWE = (size_t)HDIM*H2DIM;
  u16* w1t  = (u16*)d_out + NE;
  u16* w2t  = w1t + SWE;
  u16* w1td = w1t + 2*SWE;
  u16* w2td = w1t + 3*SWE;                    // ends < output0 end

  char* w = (char*)d_ws;
  size_t off = 0;
  u16* vbuf = (u16*)(w+off); off += NE*2;                    // bf16; also h2 alias
  u16* h1b  = (u16*)(w+off); off += (size_t)N_TOK*H2DIM*2;   // bf16; ln_gelu in-place
  u16* memb = h1b;                                            // alias: live enc-end..gather
  float* a2f = (float*)(w+off); off += (size_t)N_TOK*4;
  float* iva = (float*)(w+off); off += (size_t)N_TOK*4;
  off = (off+15)&~(size_t)15;
  float4* pmeta = (float4*)(w+off); off += (size_t)PMEM*16;
  u32* plist = (u32*)(w+off); off += (size_t)N_TOK*2*16*4;   // [token][half][16]
  (void)in_sizes; (void)n_in; (void)out_size; (void)ws_size;

  dim3 blk(256);
  transpose_f2b<<<dim3(H2DIM/32, HDIM/32), blk, 0, stream>>>(ew1, w1t,  HDIM,  H2DIM);
  transpose_f2b<<<dim3(HDIM/32, H2DIM/32), blk, 0, stream>>>(ew2, w2t,  H2DIM, HDIM);
  transpose_f2b<<<dim3(H2DIM/32, HDIM/32), blk, 0, stream>>>(dw1, w1td, HDIM,  H2DIM);
  transpose_f2b<<<dim3(HDIM/32, H2DIM/32), blk, 0, stream>>>(dw2, w2td, H2DIM, HDIM);
  // encoder
  log0_rows<<<N_TOK, blk, 0, stream>>>(x, vbuf);
  gemm_bt<<<dim3(H2DIM/128, N_TOK/128), blk, 0, stream>>>(vbuf, w1t, eb1, h1b, N_TOK, H2DIM, HDIM);
  ln_gelu<<<N_TOK, blk, 0, stream>>>(h1b, eg, ebe, h1b);
  gemm_bt<<<dim3(HDIM/128, N_TOK/128), blk, 0, stream>>>(h1b, w2t, eb2, vbuf, N_TOK, HDIM, H2DIM);
  exp0_rows<<<N_TOK, blk, 0, stream>>>(vbuf, out1, patb, a2f, iva);
  // retrieval (memb aliases h1b — dead between encoder and decoder)
  prep_mem<<<PMEM, blk, 0, stream>>>(mem, imp, memb, pmeta);
  dist_topk<<<dim3(N_TOK/16, 2), blk, 0, stream>>>(patb, memb, a2f, iva, pmeta, plist);
  gather_log0<<<N_TOK, blk, 0, stream>>>(plist, memb, vbuf);
  // decoder
  gemm_bt<<<dim3(H2DIM/128, N_TOK/128), blk, 0, stream>>>(vbuf, w1td, db1, h1b, N_TOK, H2DIM, HDIM);
  ln_gelu<<<N_TOK, blk, 0, stream>>>(h1b, dg, dbe, h1b);
  gemm_bt<<<dim3(HDIM/128, N_TOK/128), blk, 0, stream>>>(h1b, w2td, db2, vbuf, N_TOK, HDIM, H2DIM);
  exp0_rows<<<N_TOK, blk, 0, stream>>>(vbuf, out0, nullptr, nullptr, nullptr);
}

// Round 6
// 936.164 us; speedup vs baseline: 1.4939x; 1.3421x over previous
//
#include <hip/hip_runtime.h>

// PatternLearner on MI355X (gfx950). Inputs fp32, outputs fp32.
// d_out = [output0 (N*H) | output1=pattern (N*H)] fp32.
// Scratch-in-d_out: patb(bf16) bytes [0,12.58M), w1t..w2td bytes [12.58M,22.02M)
// — inside output0's byte range, overwritten only by the final exp0.
// dist_topk v3: staged-GEMM structure. 64 tokens/block (1 wave = 16 tokens),
// 128-pattern chunks staged to LDS via global_load_lds (16B, XOR-chunk-swizzle),
// per-wave survivor-filtered top-16, pattern-split 8, merge in gather_log0.

#define N_TOK 8192
#define HDIM  768
#define H2DIM 1536
#define PMEM  8192
#define KTOP  16
#define DSPLIT 8
#define CHUNK_N 128
#define DCHUNKS (PMEM/DSPLIT/CHUNK_N)   // 8
#define BKD 64

typedef __attribute__((ext_vector_type(8))) short bf16x8;   // 8 bf16 = 4 VGPRs
typedef __attribute__((ext_vector_type(4))) float f32x4;
typedef unsigned short u16;
typedef unsigned int   u32;

__device__ __forceinline__ float bf2f(u16 u){ return __uint_as_float(((u32)u)<<16); }
__device__ __forceinline__ u16 f2bf(float f){
  u32 x = __float_as_uint(f);
  return (u16)((x + 0x7FFFu + ((x>>16)&1u)) >> 16);   // RNE
}
__device__ __forceinline__ void lds_dma16(const void* g, void* l){
  __builtin_amdgcn_global_load_lds(
      (const __attribute__((address_space(1))) void*)g,
      (__attribute__((address_space(3))) void*)l, 16, 0, 0);
}

__device__ __forceinline__ float block_sum(float s){
  #pragma unroll
  for (int o=32;o;o>>=1) s += __shfl_xor(s,o);
  __shared__ float ps[4];
  int tid = threadIdx.x;
  if ((tid&63)==0) ps[tid>>6] = s;
  __syncthreads();
  return ps[0]+ps[1]+ps[2]+ps[3];
}

// ---- log0: v = atanh(nc)*x/nc. fp32 in, bf16 out ----
__global__ __launch_bounds__(256) void log0_rows(const float* __restrict__ in, u16* __restrict__ out){
  int r = blockIdx.x, tid = threadIdx.x;
  size_t ro = (size_t)r*HDIM;
  float v0=in[ro+tid], v1=in[ro+tid+256], v2=in[ro+tid+512];
  float s = block_sum(v0*v0+v1*v1+v2*v2);
  float n = sqrtf(s);
  float nc = fminf(fmaxf(n, 1e-5f), 1.0f-1e-5f);
  float sc = atanhf(nc)/nc;
  u16* orow = out + ro;
  orow[tid]=f2bf(v0*sc); orow[tid+256]=f2bf(v1*sc); orow[tid+512]=f2bf(v2*sc);
}

// ---- exp0: y = tanh(nm)*x/nm. bf16 in; fp32 out (+optional bf16 copy, a2/iva)
__global__ __launch_bounds__(256) void exp0_rows(const u16* __restrict__ in, float* __restrict__ outf,
                                                 u16* outb, float* a2p, float* ivp){
  int r = blockIdx.x, tid = threadIdx.x;
  const u16* row = in + (size_t)r*HDIM;
  float v0=bf2f(row[tid]), v1=bf2f(row[tid+256]), v2=bf2f(row[tid+512]);
  float s = block_sum(v0*v0+v1*v1+v2*v2);
  float n = sqrtf(s);
  float nm = fmaxf(n, 1e-5f);
  float sc = tanhf(nm)/nm;
  size_t ro = (size_t)r*HDIM;
  outf[ro+tid]=v0*sc; outf[ro+tid+256]=v1*sc; outf[ro+tid+512]=v2*sc;
  if (outb != nullptr){
    outb[ro+tid]=f2bf(v0*sc); outb[ro+tid+256]=f2bf(v1*sc); outb[ro+tid+512]=f2bf(v2*sc);
  }
  if (a2p != nullptr && tid==0){
    float a2 = fminf(sc*sc*s, 1.0f-1e-5f);
    a2p[r] = a2; ivp[r] = 1.0f/(1.0f-a2);
  }
}

// ---- memory prep: memb(bf16), pmeta = {b2, 1/(1-b2), sigmoid(imp), 0} ----
__global__ __launch_bounds__(256) void prep_mem(const float* __restrict__ mem, const float* __restrict__ imp,
                                                u16* __restrict__ memb, float4* __restrict__ pmeta){
  int p = blockIdx.x, tid = threadIdx.x;
  size_t ro = (size_t)p*HDIM;
  float v0=mem[ro+tid], v1=mem[ro+tid+256], v2=mem[ro+tid+512];
  memb[ro+tid]=f2bf(v0); memb[ro+tid+256]=f2bf(v1); memb[ro+tid+512]=f2bf(v2);
  float s = block_sum(v0*v0+v1*v1+v2*v2);
  if (tid==0){
    float b2 = fminf(s, 1.0f-1e-5f);
    float4 m; m.x=b2; m.y=1.0f/(1.0f-b2); m.z=1.0f/(1.0f+__expf(-imp[p])); m.w=0.f;
    pmeta[p]=m;
  }
}

// ---- LayerNorm + exact gelu over rows of 1536; in-place safe ----
__global__ __launch_bounds__(256) void ln_gelu(const u16* __restrict__ in, const float* __restrict__ g,
                                               const float* __restrict__ be, u16* __restrict__ out){
  int r = blockIdx.x, tid = threadIdx.x;
  const u16* row = in + (size_t)r*H2DIM;
  float h[6]; float s=0.f, s2=0.f;
  #pragma unroll
  for (int j=0;j<6;j++){ float v=bf2f(row[tid+256*j]); h[j]=v; s+=v; s2+=v*v; }
  #pragma unroll
  for (int o=32;o;o>>=1){ s += __shfl_xor(s,o); s2 += __shfl_xor(s2,o); }
  __shared__ float ps[4], ps2[4];
  if ((tid&63)==0){ ps[tid>>6]=s; ps2[tid>>6]=s2; }
  __syncthreads();
  s = ps[0]+ps[1]+ps[2]+ps[3]; s2 = ps2[0]+ps2[1]+ps2[2]+ps2[3];
  float mu  = s*(1.0f/H2DIM);
  float var = fmaxf(s2*(1.0f/H2DIM) - mu*mu, 0.0f);
  float rstd = rsqrtf(var + 1e-5f);
  u16* orow = out + (size_t)r*H2DIM;
  #pragma unroll
  for (int j=0;j<6;j++){
    int c = tid+256*j;
    float y = (h[j]-mu)*rstd*g[c] + be[c];
    float ge = 0.5f*y*(1.0f + erff(y*0.70710678118654752f));
    orow[c] = f2bf(ge);
  }
}

// ---- GEMM: C[M,N] = A[M,K]*BT[N,K]^T + bias; bf16 in/out, fp32 acc/bias ----
__global__ __launch_bounds__(256,2) void gemm_bt(
    const u16* __restrict__ A, const u16* __restrict__ B,
    const float* __restrict__ bias, u16* __restrict__ C,
    int M, int Nn, int Kk)
{
  __shared__ u16 As[128][40];
  __shared__ u16 Bs[128][40];
  const int tid = threadIdx.x;
  const int m0 = blockIdx.y*128, n0 = blockIdx.x*128;
  const int wave = tid>>6, lane = tid&63;
  const int wm = (wave>>1)*64, wn = (wave&1)*64;
  const int col = lane&15, quad = lane>>4;
  const int sr = tid>>1, scol = (tid&1)*16;
  f32x4 acc[4][4] = {};
  for (int k0=0; k0<Kk; k0+=32){
    bf16x8 av0 = *(const bf16x8*)(A + (size_t)(m0+sr)*Kk + k0 + scol);
    bf16x8 av1 = *(const bf16x8*)(A + (size_t)(m0+sr)*Kk + k0 + scol + 8);
    bf16x8 bv0 = *(const bf16x8*)(B + (size_t)(n0+sr)*Kk + k0 + scol);
    bf16x8 bv1 = *(const bf16x8*)(B + (size_t)(n0+sr)*Kk + k0 + scol + 8);
    __syncthreads();
    *(bf16x8*)&As[sr][scol] = av0;  *(bf16x8*)&As[sr][scol+8] = av1;
    *(bf16x8*)&Bs[sr][scol] = bv0;  *(bf16x8*)&Bs[sr][scol+8] = bv1;
    __syncthreads();
    bf16x8 af[4], bfr[4];
    #pragma unroll
    for (int i=0;i<4;i++) af[i]  = *(const bf16x8*)&As[wm+i*16+col][quad*8];
    #pragma unroll
    for (int j=0;j<4;j++) bfr[j] = *(const bf16x8*)&Bs[wn+j*16+col][quad*8];
    #pragma unroll
    for (int i=0;i<4;i++)
      #pragma unroll
      for (int j=0;j<4;j++)
        acc[i][j] = __builtin_amdgcn_mfma_f32_16x16x32_bf16(af[i], bfr[j], acc[i][j], 0,0,0);
  }
  #pragma unroll
  for (int j=0;j<4;j++){
    int cc = n0 + wn + j*16 + col;
    float bv = bias[cc];
    #pragma unroll
    for (int i=0;i<4;i++){
      int rbase = m0 + wm + i*16 + quad*4;
      #pragma unroll
      for (int rr=0;rr<4;rr++)
        C[(size_t)(rbase+rr)*Nn + cc] = f2bf(acc[i][j][rr] + bv);
    }
  }
}

// ---- transpose fp32 -> bf16 ----
__global__ __launch_bounds__(256) void transpose_f2b(const float* __restrict__ in, u16* __restrict__ out,
                                                     int R, int Ccols){
  __shared__ float tile[32][33];
  int tx = threadIdx.x & 31, ty = threadIdx.x >> 5;
  int c0 = blockIdx.x*32, r0 = blockIdx.y*32;
  #pragma unroll
  for (int i=0;i<32;i+=8) tile[ty+i][tx] = in[(size_t)(r0+ty+i)*Ccols + c0+tx];
  __syncthreads();
  #pragma unroll
  for (int i=0;i<32;i+=8) out[(size_t)(c0+ty+i)*R + r0+tx] = f2bf(tile[tx][ty+i]);
}

// ---- dist_topk v3: staged-GEMM + per-wave top-16 ----
// grid (N_TOK/64, DSPLIT). Block: 64 tokens (wave w owns tokens t0+w*16..+16),
// sweeps PMEM/DSPLIT patterns in chunks of 128. K staged in steps of 64 via
// global_load_lds with XOR chunk swizzle (chunk kc of row r holds global
// chunk kc^(r&7)), so ds_read_b128 is ≤2-way conflicted without padding.
// packed key = (dist_f32_bits & ~0x1FFF) | pattern_idx.
__global__ __launch_bounds__(256,3) void dist_topk(
    const u16* __restrict__ patb, const u16* __restrict__ memb,
    const float* __restrict__ a2f, const float* __restrict__ iva,
    const float4* __restrict__ pmeta, u32* __restrict__ plist)
{
  __shared__ u16 Atile[64*64];       // 8 KB   (64 tokens x 64 K, swizzled)
  __shared__ u16 Btile[128*64];      // 16 KB  (128 patterns x 64 K, swizzled)
  __shared__ u32 cand[4][64][17];    // 17.4 KB survivor keys [wave][pcol][token]
  __shared__ u32 lists[4][16][17];   // per-wave sorted-16 ascending
  __shared__ u32 masks[4][64];
  __shared__ float a2s[4][16], ivs[4][16];
  const int tid = threadIdx.x;
  const int wave = tid>>6, lane = tid&63;
  const int col = lane&15, quad = lane>>4;
  const int t0 = blockIdx.x*64;
  const int s  = blockIdx.y;
  const int pb0 = s*(PMEM/DSPLIT);
  if (lane<16){
    a2s[wave][lane] = a2f[t0 + wave*16 + lane];
    ivs[wave][lane] = iva[t0 + wave*16 + lane];
    #pragma unroll
    for (int j=0;j<17;j++) lists[wave][lane][j] = 0xFFFFFFFFu;
  }
  __syncthreads();
  for (int nc=0; nc<DCHUNKS; nc++){
    const int pbase = pb0 + nc*CHUNK_N;
    f32x4 acc[8] = {};
    for (int ks=0; ks<12; ks++){
      const int k0 = ks*BKD;
      __syncthreads();                      // tiles free (prev MFMA done)
      // stage A: 512 x 16B chunks; lane -> chunks {j*256 + wave*64 + lane}
      #pragma unroll
      for (int j=0;j<2;j++){
        int c = j*256 + wave*64 + lane;
        int r = c>>3, kc = c&7;
        const u16* src = patb + (size_t)(t0+r)*HDIM + k0 + ((kc ^ (r&7))*8);
        lds_dma16(src, Atile + (size_t)(j*256 + wave*64)*8);
      }
      // stage B: 1024 x 16B chunks
      #pragma unroll
      for (int j=0;j<4;j++){
        int c = j*256 + wave*64 + lane;
        int r = c>>3, kc = c&7;
        const u16* src = memb + (size_t)(pbase+r)*HDIM + k0 + ((kc ^ (r&7))*8);
        lds_dma16(src, Btile + (size_t)(j*256 + wave*64)*8);
      }
      __syncthreads();                      // vmcnt(0) drained before barrier
      // MFMA: 16 tokens x 128 patterns per wave, K=64
      #pragma unroll
      for (int kk=0;kk<2;kk++){
        const int kq = kk*4 + quad;
        const int ar = wave*16 + col;
        bf16x8 a = *(const bf16x8*)&Atile[ar*64 + ((kq ^ (ar&7))*8)];
        #pragma unroll
        for (int j=0;j<8;j++){
          const int br = j*16 + col;
          bf16x8 b = *(const bf16x8*)&Btile[br*64 + ((kq ^ (br&7))*8)];
          acc[j] = __builtin_amdgcn_mfma_f32_16x16x32_bf16(a, b, acc[j], 0,0,0);
        }
      }
    }
    // selection: two passes of 64 patterns (j<4, j>=4)
    #pragma unroll
    for (int p=0;p<2;p++){
      u32 thrU[4];
      #pragma unroll
      for (int rr=0;rr<4;rr++) thrU[rr] = lists[wave][quad*4+rr][15];
      u32 mask = 0;
      #pragma unroll
      for (int j4=0;j4<4;j4++){
        const int j = p*4 + j4;
        const int pglob = pbase + j*16 + col;
        float4 mt = pmeta[pglob];
        #pragma unroll
        for (int rr=0;rr<4;rr++){
          const int tt = quad*4 + rr;
          float num = fmaxf(a2s[wave][tt] + mt.x - 2.0f*acc[j][rr], 0.0f);
          float arg = fmaf(2.0f*num, ivs[wave][tt]*mt.y, 1.0f);
          arg = fmaxf(arg, 1.0000001f);
          float d = __logf(arg + sqrtf((arg-1.0f)*(arg+1.0f))) * mt.z;  // acosh*sig
          u32 key = (__float_as_uint(d) & 0xFFFFE000u) | (u32)pglob;
          if (key < thrU[rr]){
            cand[wave][j4*16+col][tt] = key;
            mask |= 1u << (j4*4 + rr);
          }
        }
      }
      masks[wave][lane] = mask;
      __syncthreads();
      if (lane < 16){                       // lane = token tt within wave
        const int g = lane>>2, rr = lane&3;
        u32* lst = &lists[wave][lane][0];
        u32 worst = lst[15];
        #pragma unroll 4
        for (int q=0;q<16;q++){
          u32 m = (masks[wave][g*16+q] >> rr) & 0x1111u;
          while (m){
            int b2 = __ffs(m)-1; m &= m-1;
            u32 v = cand[wave][(b2>>2)*16+q][lane];
            if (v < worst){
              int jj = 15;
              while (jj>0 && lst[jj-1] > v){ lst[jj] = lst[jj-1]; --jj; }
              lst[jj] = v;
              worst = lst[15];
            }
          }
        }
      }
      __syncthreads();
    }
  }
  if (lane < 16){
    u32* dst = plist + ((size_t)(t0 + wave*16 + lane)*DSPLIT + s)*16;
    #pragma unroll
    for (int j=0;j<16;j++) dst[j] = lists[wave][lane][j];
  }
}

// ---- fused: merge DSPLIT lists/token, gather, log0 ----
__global__ __launch_bounds__(256) void gather_log0(
    const u32* __restrict__ plist, const u16* __restrict__ memb, u16* __restrict__ out)
{
  __shared__ float wsh[KTOP]; __shared__ int ish[KTOP];
  int n = blockIdx.x, tid = threadIdx.x;
  if (tid == 0){
    const u32* l = plist + (size_t)n*DSPLIT*16;
    int ptr[DSPLIT];
    #pragma unroll
    for (int i=0;i<DSPLIT;i++) ptr[i]=0;
    #pragma unroll
    for (int j=0;j<KTOP;j++){
      u32 best = 0xFFFFFFFFu; int bw = 0;
      #pragma unroll
      for (int i=0;i<DSPLIT;i++){
        u32 v = (ptr[i]<16) ? l[i*16+ptr[i]] : 0xFFFFFFFFu;
        if (v < best){ best = v; bw = i; }
      }
      ptr[bw]++;
      wsh[j] = __expf(-__uint_as_float(best & 0xFFFFE000u));
      ish[j] = (int)(best & 0x1FFFu);
    }
  }
  __syncthreads();
  float v[3];
  #pragma unroll
  for (int j=0;j<3;j++){
    int cdx = tid + 256*j;
    float sv = 0.f;
    #pragma unroll
    for (int k=0;k<KTOP;k++) sv += wsh[k]*bf2f(memb[(size_t)ish[k]*HDIM + cdx]);
    v[j] = sv;
  }
  float ss = block_sum(v[0]*v[0]+v[1]*v[1]+v[2]*v[2]);
  float nn = sqrtf(ss);
  float nc = fminf(fmaxf(nn, 1e-5f), 1.0f-1e-5f);
  float sc = atanhf(nc)/nc;
  #pragma unroll
  for (int j=0;j<3;j++) out[(size_t)n*HDIM + tid + 256*j] = f2bf(v[j]*sc);
}

extern "C" void kernel_launch(void* const* d_in, const int* in_sizes, int n_in,
                              void* d_out, int out_size, void* d_ws, size_t ws_size,
                              hipStream_t stream)
{
  const float* x    = (const float*)d_in[0];
  const float* ew1  = (const float*)d_in[1];
  const float* eb1  = (const float*)d_in[2];
  const float* eg   = (const float*)d_in[3];
  const float* ebe  = (const float*)d_in[4];
  const float* ew2  = (const float*)d_in[5];
  const float* eb2  = (const float*)d_in[6];
  const float* dw1  = (const float*)d_in[7];
  const float* db1  = (const float*)d_in[8];
  const float* dg   = (const float*)d_in[9];
  const float* dbe  = (const float*)d_in[10];
  const float* dw2  = (const float*)d_in[11];
  const float* db2  = (const float*)d_in[12];
  const float* mem  = (const float*)d_in[13];
  const float* imp  = (const float*)d_in[14];

  const size_t NE = (size_t)N_TOK*HDIM;       // 6,291,456
  float* out0 = (float*)d_out;                // fp32 output 0
  float* out1 = out0 + NE;                    // fp32 output 1 (pattern)
  u16* patb = (u16*)d_out;                    // bf16 pattern, inside output0 range
  const size_t SWE = (size_t)HDIM*H2DIM;
  u16* w1t  = (u16*)d_out + NE;
  u16* w2t  = w1t + SWE;
  u16* w1td = w1t + 2*SWE;
  u16* w2td = w1t + 3*SWE;                    // ends < output0 end

  char* w = (char*)d_ws;
  size_t off = 0;
  u16* vbuf = (u16*)(w+off); off += NE*2;                    // bf16; also h2 alias
  u16* h1b  = (u16*)(w+off); off += (size_t)N_TOK*H2DIM*2;   // bf16; ln_gelu in-place
  u16* memb = h1b;                                            // alias: live enc-end..gather
  float* a2f = (float*)(w+off); off += (size_t)N_TOK*4;
  float* iva = (float*)(w+off); off += (size_t)N_TOK*4;
  off = (off+15)&~(size_t)15;
  float4* pmeta = (float4*)(w+off); off += (size_t)PMEM*16;
  u32* plist = (u32*)(w+off); off += (size_t)N_TOK*DSPLIT*16*4;  // 4 MB
  (void)in_sizes; (void)n_in; (void)out_size; (void)ws_size;

  dim3 blk(256);
  transpose_f2b<<<dim3(H2DIM/32, HDIM/32), blk, 0, stream>>>(ew1, w1t,  HDIM,  H2DIM);
  transpose_f2b<<<dim3(HDIM/32, H2DIM/32), blk, 0, stream>>>(ew2, w2t,  H2DIM, HDIM);
  transpose_f2b<<<dim3(H2DIM/32, HDIM/32), blk, 0, stream>>>(dw1, w1td, HDIM,  H2DIM);
  transpose_f2b<<<dim3(HDIM/32, H2DIM/32), blk, 0, stream>>>(dw2, w2td, H2DIM, HDIM);
  // encoder
  log0_rows<<<N_TOK, blk, 0, stream>>>(x, vbuf);
  gemm_bt<<<dim3(H2DIM/128, N_TOK/128), blk, 0, stream>>>(vbuf, w1t, eb1, h1b, N_TOK, H2DIM, HDIM);
  ln_gelu<<<N_TOK, blk, 0, stream>>>(h1b, eg, ebe, h1b);
  gemm_bt<<<dim3(HDIM/128, N_TOK/128), blk, 0, stream>>>(h1b, w2t, eb2, vbuf, N_TOK, HDIM, H2DIM);
  exp0_rows<<<N_TOK, blk, 0, stream>>>(vbuf, out1, patb, a2f, iva);
  // retrieval (memb aliases h1b — dead between encoder and decoder)
  prep_mem<<<PMEM, blk, 0, stream>>>(mem, imp, memb, pmeta);
  dist_topk<<<dim3(N_TOK/64, DSPLIT), blk, 0, stream>>>(patb, memb, a2f, iva, pmeta, plist);
  gather_log0<<<N_TOK, blk, 0, stream>>>(plist, memb, vbuf);
  // decoder
  gemm_bt<<<dim3(H2DIM/128, N_TOK/128), blk, 0, stream>>>(vbuf, w1td, db1, h1b, N_TOK, H2DIM, HDIM);
  ln_gelu<<<N_TOK, blk, 0, stream>>>(h1b, dg, dbe, h1b);
  gemm_bt<<<dim3(HDIM/128, N_TOK/128), blk, 0, stream>>>(h1b, w2td, db2, vbuf, N_TOK, HDIM, H2DIM);
  exp0_rows<<<N_TOK, blk, 0, stream>>>(vbuf, out0, nullptr, nullptr, nullptr);
}